// Round 4
// baseline (240.939 us; speedup 1.0000x reference)
//
#include <hip/hip_runtime.h>
#include <stdint.h>

constexpr int BN_ = 8192;   // batch
constexpr int DD = 256;     // feature dim
constexpr int NCLS = 16;
constexpr float INV_T = 1.0f / 0.07f;

typedef float f32x4 __attribute__((ext_vector_type(4)));

// ---- kernel 1: histogram + class-grouped permutation + zero accumulators ----
__global__ __launch_bounds__(256) void setup_kernel(const int* __restrict__ labels,
                                                    int* __restrict__ counts,
                                                    int* __restrict__ starts,
                                                    int* __restrict__ perm,
                                                    int* __restrict__ labp,
                                                    int* __restrict__ num_valid,
                                                    float* __restrict__ neg_sum,
                                                    float* __restrict__ total_loss) {
  __shared__ int scnt[NCLS], sfill[NCLS];
  int tid = threadIdx.x;
  for (int i = tid; i < BN_; i += 256) neg_sum[i] = 0.0f;  // ws is poisoned 0xAA
  if (tid == 0) *total_loss = 0.0f;
  if (tid < NCLS) scnt[tid] = 0;
  __syncthreads();
  for (int i = tid; i < BN_; i += 256) atomicAdd(&scnt[labels[i]], 1);
  __syncthreads();
  if (tid == 0) {
    int acc = 0, nv = 0;
    for (int c = 0; c < NCLS; ++c) {
      sfill[c] = acc;
      counts[c] = scnt[c];
      starts[c] = acc;
      if (scnt[c] >= 2 && scnt[c] < BN_) nv += scnt[c];  // num_pos>0 && num_neg>0
      acc += scnt[c];
    }
    *num_valid = nv;
  }
  __syncthreads();
  for (int i = tid; i < BN_; i += 256) {
    int c = labels[i];
    int pos = atomicAdd(&sfill[c], 1);
    perm[pos] = i;
    labp[pos] = c;
  }
}

// ---- kernel 2: permuted gather fp32 -> fp8 e4m3 (OCP, hw packed cvt) ----
__global__ __launch_bounds__(256) void convert_kernel(const float* __restrict__ F,
                                                      const int* __restrict__ perm,
                                                      unsigned char* __restrict__ Ff) {
  int t = blockIdx.x * 256 + threadIdx.x;
  int row = t >> 6;            // 64 threads per 256-elem row
  int off = (t & 63) * 4;
  int src = perm[row];
  float4 v = *(const float4*)(F + (size_t)src * DD + off);
  int p = __builtin_amdgcn_cvt_pk_fp8_f32(v.x, v.y, 0, false);
  p = __builtin_amdgcn_cvt_pk_fp8_f32(v.z, v.w, p, true);
  *(unsigned int*)(Ff + (size_t)row * DD + off) = (unsigned int)p;
}

// ---- kernel 3: symmetric fused fp8 GEMM -> exp -> label-masked neg sums ----
// Barrier-free streaming from L2-resident Ff (2 MB < 4 MB/XCD L2). Fragment
// double-buffer: load k+1 frags while issuing k's MFMAs. Upper-triangle tiles;
// off-diag tiles also accumulate column sums via symmetry e_ij == e_ji.
__global__ __launch_bounds__(256, 4) void pass1_kernel(const unsigned char* __restrict__ Ff,
                                                       const int* __restrict__ labp,
                                                       float* __restrict__ neg_sum) {
  const int rT = blockIdx.y, cT = blockIdx.x;
  if (cT < rT) return;                               // upper triangle incl. diagonal
  const int rBase = rT * 128, cBase = cT * 128;

  __shared__ int rlab[128], clab[128];
  const int tid = threadIdx.x;
  if (tid < 128) {
    rlab[tid] = labp[rBase + tid];
    clab[tid] = labp[cBase + tid];
  }

  const int wave = tid >> 6, lane = tid & 63;
  const int wm = wave >> 1, wn = wave & 1;
  const int quad = lane >> 4, l16 = lane & 15;

  // A-frag layout for mfma_f32_16x16x32_fp8_fp8: row = l16, k = quad*8 + j
  const unsigned char* Ab[4];
  const unsigned char* Bb[4];
#pragma unroll
  for (int im = 0; im < 4; ++im)
    Ab[im] = Ff + (size_t)(rBase + wm * 64 + im * 16 + l16) * DD + quad * 8;
#pragma unroll
  for (int in = 0; in < 4; ++in)
    Bb[in] = Ff + (size_t)(cBase + wn * 64 + in * 16 + l16) * DD + quad * 8;

  f32x4 acc[4][4] = {};
  long a_cur[4], b_cur[4], a_nxt[4], b_nxt[4];
#pragma unroll
  for (int im = 0; im < 4; ++im) a_cur[im] = *(const long*)(Ab[im]);
#pragma unroll
  for (int in = 0; in < 4; ++in) b_cur[in] = *(const long*)(Bb[in]);

#pragma unroll
  for (int k0 = 0; k0 < DD; k0 += 32) {
    if (k0 + 32 < DD) {
#pragma unroll
      for (int im = 0; im < 4; ++im) a_nxt[im] = *(const long*)(Ab[im] + k0 + 32);
#pragma unroll
      for (int in = 0; in < 4; ++in) b_nxt[in] = *(const long*)(Bb[in] + k0 + 32);
    }
#pragma unroll
    for (int im = 0; im < 4; ++im)
#pragma unroll
      for (int in = 0; in < 4; ++in)
        acc[im][in] = __builtin_amdgcn_mfma_f32_16x16x32_fp8_fp8(a_cur[im], b_cur[in], acc[im][in], 0, 0, 0);
#pragma unroll
    for (int im = 0; im < 4; ++im) a_cur[im] = a_nxt[im];
#pragma unroll
    for (int in = 0; in < 4; ++in) b_cur[in] = b_nxt[in];
  }

  __syncthreads();  // rlab/clab visible to all waves

  // C/D layout (dtype-independent, verified m89): col = lane&15, row = quad*4 + reg
  const bool offDiag = (cT != rT);
  float cpart[4] = {0.f, 0.f, 0.f, 0.f};
#pragma unroll
  for (int im = 0; im < 4; ++im) {
    float rsum[4] = {0.f, 0.f, 0.f, 0.f};
#pragma unroll
    for (int in = 0; in < 4; ++in) {
      int lc = clab[wn * 64 + in * 16 + l16];
#pragma unroll
      for (int r = 0; r < 4; ++r) {
        int row = wm * 64 + im * 16 + quad * 4 + r;
        float e = __expf(acc[im][in][r] * INV_T);
        float me = (rlab[row] != lc) ? e : 0.0f;
        rsum[r] += me;
        cpart[in] += me;
      }
    }
#pragma unroll
    for (int r = 0; r < 4; ++r) {
#pragma unroll
      for (int off = 1; off < 16; off <<= 1)
        rsum[r] += __shfl_xor(rsum[r], off, 64);
      if (l16 == 0)
        atomicAdd(&neg_sum[rBase + wm * 64 + im * 16 + quad * 4 + r], rsum[r]);
    }
  }
  if (offDiag) {
#pragma unroll
    for (int in = 0; in < 4; ++in) {
      cpart[in] += __shfl_xor(cpart[in], 16, 64);
      cpart[in] += __shfl_xor(cpart[in], 32, 64);
      if (quad == 0)
        atomicAdd(&neg_sum[cBase + wn * 64 + in * 16 + l16], cpart[in]);
    }
  }
}

// ---- kernel 4: block-diagonal positive-pair fp8 GEMM + fused loss epilogue ----
__global__ __launch_bounds__(256, 4) void pass3_kernel(const unsigned char* __restrict__ Ff,
                                                       const int* __restrict__ counts,
                                                       const int* __restrict__ starts,
                                                       const float* __restrict__ neg_sum,
                                                       float* __restrict__ total_loss) {
  const int c = blockIdx.z;
  const int cnt = counts[c];
  if (cnt < 2 || cnt >= BN_) return;                 // invalid class: no contribution
  const int rT = blockIdx.y, cT = blockIdx.x;
  if (cT < rT) return;
  const int r0 = rT * 128, c0 = cT * 128;
  if (r0 >= cnt || c0 >= cnt) return;
  const int start = starts[c];

  __shared__ float rneg[128], cneg[128];
  const int tid = threadIdx.x;
  if (tid < 128) {
    rneg[tid] = neg_sum[start + min(r0 + tid, cnt - 1)];
    cneg[tid] = neg_sum[start + min(c0 + tid, cnt - 1)];
  }

  const int wave = tid >> 6, lane = tid & 63;
  const int wm = wave >> 1, wn = wave & 1;
  const int quad = lane >> 4, l16 = lane & 15;

  const unsigned char* Ab[4];
  const unsigned char* Bb[4];
#pragma unroll
  for (int im = 0; im < 4; ++im)
    Ab[im] = Ff + (size_t)(start + min(r0 + wm * 64 + im * 16 + l16, cnt - 1)) * DD + quad * 8;
#pragma unroll
  for (int in = 0; in < 4; ++in)
    Bb[in] = Ff + (size_t)(start + min(c0 + wn * 64 + in * 16 + l16, cnt - 1)) * DD + quad * 8;

  f32x4 acc[4][4] = {};
  long a_cur[4], b_cur[4], a_nxt[4], b_nxt[4];
#pragma unroll
  for (int im = 0; im < 4; ++im) a_cur[im] = *(const long*)(Ab[im]);
#pragma unroll
  for (int in = 0; in < 4; ++in) b_cur[in] = *(const long*)(Bb[in]);

#pragma unroll
  for (int k0 = 0; k0 < DD; k0 += 32) {
    if (k0 + 32 < DD) {
#pragma unroll
      for (int im = 0; im < 4; ++im) a_nxt[im] = *(const long*)(Ab[im] + k0 + 32);
#pragma unroll
      for (int in = 0; in < 4; ++in) b_nxt[in] = *(const long*)(Bb[in] + k0 + 32);
    }
#pragma unroll
    for (int im = 0; im < 4; ++im)
#pragma unroll
      for (int in = 0; in < 4; ++in)
        acc[im][in] = __builtin_amdgcn_mfma_f32_16x16x32_fp8_fp8(a_cur[im], b_cur[in], acc[im][in], 0, 0, 0);
#pragma unroll
    for (int im = 0; im < 4; ++im) a_cur[im] = a_nxt[im];
#pragma unroll
    for (int in = 0; in < 4; ++in) b_cur[in] = b_nxt[in];
  }

  __syncthreads();

  const bool offDiag = (cT != rT);
  float bsum = 0.f;
#pragma unroll
  for (int im = 0; im < 4; ++im) {
#pragma unroll
    for (int in = 0; in < 4; ++in) {
      int colIdx = wn * 64 + in * 16 + l16;
      int gc = c0 + colIdx;
      bool cok = gc < cnt;
#pragma unroll
      for (int r = 0; r < 4; ++r) {
        int rowIdx = wm * 64 + im * 16 + quad * 4 + r;
        int gr = r0 + rowIdx;
        if (cok && gr < cnt && gr != gc) {
          float e = __expf(acc[im][in][r] * INV_T);
          bsum -= __logf(e / (e + rneg[rowIdx]) + 1e-8f);
          if (offDiag)
            bsum -= __logf(e / (e + cneg[colIdx]) + 1e-8f);  // pair (gc, gr)
        }
      }
    }
  }

  __shared__ float red[4];
#pragma unroll
  for (int off = 1; off < 64; off <<= 1) bsum += __shfl_xor(bsum, off, 64);
  if (lane == 0) red[wave] = bsum;
  __syncthreads();
  if (tid == 0) {
    float s = red[0] + red[1] + red[2] + red[3];
    atomicAdd(total_loss, s / (float)(cnt - 1));     // /num_pos (uniform per class)
  }
}

// ---- kernel 5: finalize scalar ----
__global__ void finalize_kernel(const float* __restrict__ total_loss,
                                const int* __restrict__ num_valid,
                                float* __restrict__ out) {
  float t = *total_loss;
  int n = *num_valid;
  out[0] = (n > 0) ? (t / (float)n) : 0.0f;
}

extern "C" void kernel_launch(void* const* d_in, const int* in_sizes, int n_in,
                              void* d_out, int out_size, void* d_ws, size_t ws_size,
                              hipStream_t stream) {
  (void)in_sizes; (void)n_in; (void)out_size; (void)ws_size;
  const float* F = (const float*)d_in[0];
  const int* labels = (const int*)d_in[1];
  float* out = (float*)d_out;
  char* ws = (char*)d_ws;

  // ws layout (~2.3 MB)
  unsigned char* Ff = (unsigned char*)ws;                    // 2 MB fp8 permuted features
  const size_t OFF_NEG = (size_t)2 << 20;
  float* neg_sum = (float*)(ws + OFF_NEG);                   // 32 KB
  char* misc = ws + OFF_NEG + 32768;
  float* total_loss = (float*)misc;                          // 4 B
  int* counts = (int*)(misc + 16);                           // 64 B
  int* starts = (int*)(misc + 16 + 64);                      // 64 B
  int* num_valid = (int*)(misc + 16 + 128);                  // 4 B
  int* perm = (int*)(misc + 256);                            // 32 KB
  int* labp = (int*)(misc + 256 + 32768);                    // 32 KB

  setup_kernel<<<1, 256, 0, stream>>>(labels, counts, starts, perm, labp,
                                      num_valid, neg_sum, total_loss);
  convert_kernel<<<BN_ * DD / 1024, 256, 0, stream>>>(F, perm, Ff);
  pass1_kernel<<<dim3(BN_ / 128, BN_ / 128), 256, 0, stream>>>(Ff, labp, neg_sum);
  // cnt up to 1024/class supported (8x8 tile grid); B=8192 random-16 gives
  // cnt ~= 512 +- 35, ~14 sigma of headroom
  pass3_kernel<<<dim3(8, 8, NCLS), 256, 0, stream>>>(Ff, counts, starts, neg_sum, total_loss);
  finalize_kernel<<<1, 1, 0, stream>>>(total_loss, num_valid, out);
}

// Round 5
// 145.853 us; speedup vs baseline: 1.6519x; 1.6519x over previous
//
#include <hip/hip_runtime.h>
#include <stdint.h>

constexpr int BN_ = 8192;   // batch
constexpr int DD = 256;     // feature dim
constexpr int NCLS = 16;
constexpr float INV_T = 1.0f / 0.07f;
constexpr int BPAD = 8704;       // padded row space (16-aligned classes + pass3 overreach slack)
constexpr int NGRP = BPAD / 16;  // 544 fragment row-groups
constexpr int NT1 = 66;          // pass1 tiles: 66*128 = 8448 >= max padded rows 8432

typedef float f32x4 __attribute__((ext_vector_type(4)));
typedef long long2_t __attribute__((ext_vector_type(2)));

// ---- kernel 1: histogram + 16-aligned class-grouped permutation + zeroing ----
__global__ __launch_bounds__(256) void setup_kernel(const int* __restrict__ labels,
                                                    int* __restrict__ counts,
                                                    int* __restrict__ starts16,
                                                    int* __restrict__ permp,
                                                    int* __restrict__ labp,
                                                    int* __restrict__ num_valid,
                                                    float* __restrict__ neg_sum,
                                                    float* __restrict__ total_loss) {
  __shared__ int scnt[NCLS], sfill[NCLS];
  int tid = threadIdx.x;
  for (int i = tid; i < NT1 * 128; i += 256) neg_sum[i] = 0.0f;   // ws poisoned 0xAA
  for (int i = tid; i < BPAD; i += 256) { permp[i] = 0; labp[i] = -1; }
  if (tid == 0) *total_loss = 0.0f;
  if (tid < NCLS) scnt[tid] = 0;
  __syncthreads();
  for (int i = tid; i < BN_; i += 256) atomicAdd(&scnt[labels[i]], 1);
  __syncthreads();
  if (tid == 0) {
    int acc = 0, nv = 0;
    for (int c = 0; c < NCLS; ++c) {
      counts[c] = scnt[c];
      starts16[c] = acc;                     // 16-aligned class start
      sfill[c] = acc;
      if (scnt[c] >= 2 && scnt[c] < BN_) nv += scnt[c];  // num_pos>0 && num_neg>0
      acc += (scnt[c] + 15) & ~15;           // pad to 16
    }
    *num_valid = nv;
  }
  __syncthreads();
  for (int i = tid; i < BN_; i += 256) {
    int c = labels[i];
    int pos = atomicAdd(&sfill[c], 1);
    permp[pos] = i;
    labp[pos] = c;
  }
}

// ---- kernel 2: gather fp32 -> fp8 into PACKED MFMA-fragment layout ----
// Unit: Fpk[((g*4 + kc2)*64 + lane)*16 + b]; row = g*16 + (lane&15), quad = lane>>4,
// bytes 0-7:  k = kc2*64 +      quad*8 + j   (lo chunk)
// bytes 8-15: k = kc2*64 + 32 + quad*8 + j   (hi chunk)
// => one dwordx4 per lane = two fp8 MFMA fragments, 64 lanes contiguous (1 KB burst).
__global__ __launch_bounds__(256) void convert_kernel(const float* __restrict__ F,
                                                      const int* __restrict__ permp,
                                                      unsigned char* __restrict__ Fpk) {
  const int g = blockIdx.x;
  const int t = threadIdx.x;
  const int kc2 = t >> 6, lane = t & 63;
  const int l16 = lane & 15, quad = lane >> 4;
  const int src = permp[g * 16 + l16];
  const float* fr = F + (size_t)src * DD + kc2 * 64 + quad * 8;
  float4 v0 = *(const float4*)(fr);
  float4 v1 = *(const float4*)(fr + 4);
  float4 v2 = *(const float4*)(fr + 32);
  float4 v3 = *(const float4*)(fr + 36);
  uint4 o;
  int p;
  p = __builtin_amdgcn_cvt_pk_fp8_f32(v0.x, v0.y, 0, false);
  p = __builtin_amdgcn_cvt_pk_fp8_f32(v0.z, v0.w, p, true);  o.x = (unsigned)p;
  p = __builtin_amdgcn_cvt_pk_fp8_f32(v1.x, v1.y, 0, false);
  p = __builtin_amdgcn_cvt_pk_fp8_f32(v1.z, v1.w, p, true);  o.y = (unsigned)p;
  p = __builtin_amdgcn_cvt_pk_fp8_f32(v2.x, v2.y, 0, false);
  p = __builtin_amdgcn_cvt_pk_fp8_f32(v2.z, v2.w, p, true);  o.z = (unsigned)p;
  p = __builtin_amdgcn_cvt_pk_fp8_f32(v3.x, v3.y, 0, false);
  p = __builtin_amdgcn_cvt_pk_fp8_f32(v3.z, v3.w, p, true);  o.w = (unsigned)p;
  *(uint4*)(Fpk + (((size_t)g * 4 + kc2) * 64 + lane) * 16) = o;
}

// ---- kernel 3: symmetric fused fp8 GEMM -> exp -> label-masked neg sums ----
// Coalesced packed-fragment loads (dwordx4, 64 lanes contiguous), explicit
// double-buffer over 4 k-chunk-pairs, no launch_bounds register cap.
__global__ __launch_bounds__(256) void pass1_kernel(const unsigned char* __restrict__ Fpk,
                                                    const int* __restrict__ labp,
                                                    float* __restrict__ neg_sum) {
  const int rT = blockIdx.y, cT = blockIdx.x;
  if (cT < rT) return;                        // upper triangle incl. diagonal
  __shared__ int rlab[128], clab[128];
  const int tid = threadIdx.x;
  if (tid < 128) {
    rlab[tid] = labp[rT * 128 + tid];
    clab[tid] = labp[cT * 128 + tid];
  }
  const int wave = tid >> 6, lane = tid & 63;
  const int wm = wave >> 1, wn = wave & 1;
  const int quad = lane >> 4, l16 = lane & 15;
  const int gA = rT * 8 + wm * 4;             // A fragment group base (+im)
  const int gB = cT * 8 + wn * 4;

#define FRAGP(g, kc2) ((const long2_t*)(Fpk + ((((size_t)(g)) * 4 + (kc2)) * 64 + lane) * 16))

  f32x4 acc[4][4] = {};
  long2_t a_cur[4], b_cur[4], a_nxt[4], b_nxt[4];
#pragma unroll
  for (int im = 0; im < 4; ++im) a_cur[im] = *FRAGP(gA + im, 0);
#pragma unroll
  for (int in = 0; in < 4; ++in) b_cur[in] = *FRAGP(gB + in, 0);

#pragma unroll
  for (int kc2 = 0; kc2 < 4; ++kc2) {
    if (kc2 < 3) {
#pragma unroll
      for (int im = 0; im < 4; ++im) a_nxt[im] = *FRAGP(gA + im, kc2 + 1);
#pragma unroll
      for (int in = 0; in < 4; ++in) b_nxt[in] = *FRAGP(gB + in, kc2 + 1);
    }
#pragma unroll
    for (int im = 0; im < 4; ++im)
#pragma unroll
      for (int in = 0; in < 4; ++in)
        acc[im][in] = __builtin_amdgcn_mfma_f32_16x16x32_fp8_fp8(a_cur[im].x, b_cur[in].x, acc[im][in], 0, 0, 0);
#pragma unroll
    for (int im = 0; im < 4; ++im)
#pragma unroll
      for (int in = 0; in < 4; ++in)
        acc[im][in] = __builtin_amdgcn_mfma_f32_16x16x32_fp8_fp8(a_cur[im].y, b_cur[in].y, acc[im][in], 0, 0, 0);
#pragma unroll
    for (int im = 0; im < 4; ++im) a_cur[im] = a_nxt[im];
#pragma unroll
    for (int in = 0; in < 4; ++in) b_cur[in] = b_nxt[in];
  }

  __syncthreads();  // rlab/clab visible to all waves

  // C/D layout (dtype-independent, m89): col = lane&15, row = quad*4 + reg
  const bool offDiag = (cT != rT);
  float cpart[4] = {0.f, 0.f, 0.f, 0.f};
#pragma unroll
  for (int im = 0; im < 4; ++im) {
    float rsum[4] = {0.f, 0.f, 0.f, 0.f};
#pragma unroll
    for (int in = 0; in < 4; ++in) {
      int lc = clab[wn * 64 + in * 16 + l16];
#pragma unroll
      for (int r = 0; r < 4; ++r) {
        int row = wm * 64 + im * 16 + quad * 4 + r;
        int rl = rlab[row];
        float e = __expf(acc[im][in][r] * INV_T);
        // mask: different labels AND both real (pads have label -1)
        float me = (rl != lc && ((rl | lc) >= 0)) ? e : 0.0f;
        rsum[r] += me;
        cpart[in] += me;
      }
    }
#pragma unroll
    for (int r = 0; r < 4; ++r) {
#pragma unroll
      for (int off = 1; off < 16; off <<= 1)
        rsum[r] += __shfl_xor(rsum[r], off, 64);
      if (l16 == 0)
        atomicAdd(&neg_sum[rT * 128 + wm * 64 + im * 16 + quad * 4 + r], rsum[r]);
    }
  }
  if (offDiag) {
#pragma unroll
    for (int in = 0; in < 4; ++in) {
      cpart[in] += __shfl_xor(cpart[in], 16, 64);
      cpart[in] += __shfl_xor(cpart[in], 32, 64);
      if (quad == 0)
        atomicAdd(&neg_sum[cT * 128 + wn * 64 + in * 16 + l16], cpart[in]);
    }
  }
}

// ---- kernel 4: block-diagonal positive-pair fp8 GEMM + fused loss epilogue ----
__global__ __launch_bounds__(256) void pass3_kernel(const unsigned char* __restrict__ Fpk,
                                                    const int* __restrict__ counts,
                                                    const int* __restrict__ starts16,
                                                    const float* __restrict__ neg_sum,
                                                    float* __restrict__ total_loss) {
  const int c = blockIdx.z;
  const int cnt = counts[c];
  if (cnt < 2 || cnt >= BN_) return;
  const int rT = blockIdx.y, cT = blockIdx.x;
  if (cT < rT) return;
  const int r0 = rT * 128, c0 = cT * 128;
  if (r0 >= cnt || c0 >= cnt) return;
  const int s16 = starts16[c];                 // multiple of 16
  const int sg = s16 >> 4;

  __shared__ float rneg[128], cneg[128];
  const int tid = threadIdx.x;
  if (tid < 128) {
    rneg[tid] = neg_sum[s16 + min(r0 + tid, cnt - 1)];
    cneg[tid] = neg_sum[s16 + min(c0 + tid, cnt - 1)];
  }
  const int wave = tid >> 6, lane = tid & 63;
  const int wm = wave >> 1, wn = wave & 1;
  const int quad = lane >> 4, l16 = lane & 15;
  const int gA = sg + rT * 8 + wm * 4;
  const int gB = sg + cT * 8 + wn * 4;

  f32x4 acc[4][4] = {};
  long2_t a_cur[4], b_cur[4], a_nxt[4], b_nxt[4];
#pragma unroll
  for (int im = 0; im < 4; ++im) a_cur[im] = *FRAGP(gA + im, 0);
#pragma unroll
  for (int in = 0; in < 4; ++in) b_cur[in] = *FRAGP(gB + in, 0);

#pragma unroll
  for (int kc2 = 0; kc2 < 4; ++kc2) {
    if (kc2 < 3) {
#pragma unroll
      for (int im = 0; im < 4; ++im) a_nxt[im] = *FRAGP(gA + im, kc2 + 1);
#pragma unroll
      for (int in = 0; in < 4; ++in) b_nxt[in] = *FRAGP(gB + in, kc2 + 1);
    }
#pragma unroll
    for (int im = 0; im < 4; ++im)
#pragma unroll
      for (int in = 0; in < 4; ++in)
        acc[im][in] = __builtin_amdgcn_mfma_f32_16x16x32_fp8_fp8(a_cur[im].x, b_cur[in].x, acc[im][in], 0, 0, 0);
#pragma unroll
    for (int im = 0; im < 4; ++im)
#pragma unroll
      for (int in = 0; in < 4; ++in)
        acc[im][in] = __builtin_amdgcn_mfma_f32_16x16x32_fp8_fp8(a_cur[im].y, b_cur[in].y, acc[im][in], 0, 0, 0);
#pragma unroll
    for (int im = 0; im < 4; ++im) a_cur[im] = a_nxt[im];
#pragma unroll
    for (int in = 0; in < 4; ++in) b_cur[in] = b_nxt[in];
  }

  __syncthreads();

  const bool offDiag = (cT != rT);
  float bsum = 0.f;
#pragma unroll
  for (int im = 0; im < 4; ++im) {
#pragma unroll
    for (int in = 0; in < 4; ++in) {
      int colIdx = wn * 64 + in * 16 + l16;
      int gc = c0 + colIdx;
      bool cok = gc < cnt;
#pragma unroll
      for (int r = 0; r < 4; ++r) {
        int rowIdx = wm * 64 + im * 16 + quad * 4 + r;
        int gr = r0 + rowIdx;
        if (cok && gr < cnt && gr != gc) {
          float e = __expf(acc[im][in][r] * INV_T);
          bsum -= __logf(e / (e + rneg[rowIdx]) + 1e-8f);
          if (offDiag)
            bsum -= __logf(e / (e + cneg[colIdx]) + 1e-8f);  // mirrored pair
        }
      }
    }
  }

  __shared__ float red[4];
#pragma unroll
  for (int off = 1; off < 64; off <<= 1) bsum += __shfl_xor(bsum, off, 64);
  if (lane == 0) red[wave] = bsum;
  __syncthreads();
  if (tid == 0) {
    float s = red[0] + red[1] + red[2] + red[3];
    atomicAdd(total_loss, s / (float)(cnt - 1));   // /num_pos (uniform per class)
  }
}

// ---- kernel 5: finalize scalar ----
__global__ void finalize_kernel(const float* __restrict__ total_loss,
                                const int* __restrict__ num_valid,
                                float* __restrict__ out) {
  float t = *total_loss;
  int n = *num_valid;
  out[0] = (n > 0) ? (t / (float)n) : 0.0f;
}

extern "C" void kernel_launch(void* const* d_in, const int* in_sizes, int n_in,
                              void* d_out, int out_size, void* d_ws, size_t ws_size,
                              hipStream_t stream) {
  (void)in_sizes; (void)n_in; (void)out_size; (void)ws_size;
  const float* F = (const float*)d_in[0];
  const int* labels = (const int*)d_in[1];
  float* out = (float*)d_out;
  char* ws = (char*)d_ws;

  // ws layout (~2.4 MB)
  unsigned char* Fpk = (unsigned char*)ws;                   // 544*4096 = 2.23 MB packed fp8
  const size_t OFF_NEG = (size_t)NGRP * 4096;
  float* neg_sum = (float*)(ws + OFF_NEG);                   // 8448 floats
  char* misc = ws + OFF_NEG + (size_t)NT1 * 128 * 4;
  float* total_loss = (float*)misc;                          // 4 B
  int* counts = (int*)(misc + 16);                           // 64 B
  int* starts16 = (int*)(misc + 16 + 64);                    // 64 B
  int* num_valid = (int*)(misc + 16 + 128);                  // 4 B
  int* permp = (int*)(misc + 256);                           // BPAD ints
  int* labp = (int*)(misc + 256 + BPAD * 4);                 // BPAD ints

  setup_kernel<<<1, 256, 0, stream>>>(labels, counts, starts16, permp, labp,
                                      num_valid, neg_sum, total_loss);
  convert_kernel<<<NGRP, 256, 0, stream>>>(F, permp, Fpk);
  pass1_kernel<<<dim3(NT1, NT1), 256, 0, stream>>>(Fpk, labp, neg_sum);
  // cnt up to 1024/class (8x8 tile grid); B=8192 random-16 gives ~512 +- 35
  pass3_kernel<<<dim3(8, 8, NCLS), 256, 0, stream>>>(Fpk, counts, starts16, neg_sum, total_loss);
  finalize_kernel<<<1, 1, 0, stream>>>(total_loss, num_valid, out);
}

// Round 7
// 131.511 us; speedup vs baseline: 1.8321x; 1.1091x over previous
//
#include <hip/hip_runtime.h>
#include <stdint.h>

constexpr int BN_ = 8192;   // batch
constexpr int DD = 256;     // feature dim
constexpr int NCLS = 16;
constexpr float INV_T = 1.0f / 0.07f;
constexpr int BPAD = 8704;             // padded row space (16-aligned classes + slack)
constexpr int NGRP = BPAD / 16;        // 544 fragment row-groups
constexpr int NT1 = 66;                // pass1 tile rows: 66*128 = 8448 >= max padded 8432
constexpr int NTILE1 = NT1 * (NT1 + 1) / 2;  // 2211 upper-tri tiles

typedef float f32x4 __attribute__((ext_vector_type(4)));
typedef long long2_t __attribute__((ext_vector_type(2)));

// misc layout (ints): [0] total_loss(float) [1] num_valid [2..18) gcnt
// [18..34) gstart16 [34..34+512) gpart[32][16]
#define M_TOTAL 0
#define M_NV 1
#define M_CNT 2
#define M_START 18
#define M_PART 34

__device__ __forceinline__ void async_copy16(const void* g, void* l) {
  __builtin_amdgcn_global_load_lds((const __attribute__((address_space(1))) void*)g,
                                   (__attribute__((address_space(3))) void*)l,
                                   16, 0, 0);
}

// ---- kernel 1: per-block histogram partials + zero accumulators ----
__global__ __launch_bounds__(256) void hist_kernel(const int* __restrict__ labels,
                                                   int* __restrict__ misc,
                                                   int* __restrict__ permp,
                                                   int* __restrict__ labp,
                                                   float* __restrict__ neg_sum) {
  __shared__ int scnt[NCLS];
  const int b = blockIdx.x, tid = threadIdx.x;
  const int gid = b * 256 + tid;
  // zero (ws poisoned 0xAA); strided over 8192 threads
  for (int i = gid; i < NT1 * 128; i += 8192) neg_sum[i] = 0.0f;
  for (int i = gid; i < BPAD; i += 8192) { labp[i] = -1; permp[i] = 0; }
  if (gid == 0) { ((float*)misc)[M_TOTAL] = 0.0f; misc[M_NV] = 0; }
  if (tid < NCLS) scnt[tid] = 0;
  __syncthreads();
  atomicAdd(&scnt[labels[gid]], 1);
  __syncthreads();
  if (tid < NCLS) misc[M_PART + b * 16 + tid] = scnt[tid];
}

// ---- kernel 2: deterministic rank/scatter (each block computes its base) ----
__global__ __launch_bounds__(256) void scatter_kernel(const int* __restrict__ labels,
                                                      int* __restrict__ misc,
                                                      int* __restrict__ permp,
                                                      int* __restrict__ labp) {
  __shared__ int s_cnt[NCLS], s_start[NCLS], s_base[NCLS], s_rank[NCLS];
  const int b = blockIdx.x, tid = threadIdx.x;
  const int i = b * 256 + tid;
  if (tid < NCLS) {
    int tot = 0, mybase = 0;
    for (int b2 = 0; b2 < 32; ++b2) {
      int v = misc[M_PART + b2 * 16 + tid];
      if (b2 < b) mybase += v;
      tot += v;
    }
    s_cnt[tid] = tot;
    s_base[tid] = mybase;
    s_rank[tid] = 0;
  }
  __syncthreads();
  if (tid == 0) {
    int acc = 0, nv = 0;
    for (int c = 0; c < NCLS; ++c) {
      s_start[c] = acc;
      int cc = s_cnt[c];
      if (cc >= 2 && cc < BN_) nv += cc;     // num_pos>0 && num_neg>0
      acc += (cc + 15) & ~15;                // 16-align
    }
    if (b == 0) {
      misc[M_NV] = nv;
      for (int c = 0; c < NCLS; ++c) {
        misc[M_CNT + c] = s_cnt[c];
        misc[M_START + c] = s_start[c];
      }
    }
  }
  __syncthreads();
  int c = labels[i];
  int r = atomicAdd(&s_rank[c], 1);
  int pos = s_start[c] + s_base[c] + r;
  permp[pos] = i;
  labp[pos] = c;
}

// ---- kernel 3: gather fp32 -> fp8 into PACKED MFMA-fragment layout ----
// Unit: Fpk[((g*4 + k2)*64 + lane)*16 + byte]; row = g*16 + (lane&15),
// quad = lane>>4; bytes 0-7: k = k2*64 + quad*8 + j; bytes 8-15: +32.
__global__ __launch_bounds__(256) void convert_kernel(const float* __restrict__ F,
                                                      const int* __restrict__ permp,
                                                      unsigned char* __restrict__ Fpk) {
  const int g = blockIdx.x;
  const int t = threadIdx.x;
  const int k2 = t >> 6, lane = t & 63;
  const int l16 = lane & 15, quad = lane >> 4;
  const int src = permp[g * 16 + l16];
  const float* fr = F + (size_t)src * DD + k2 * 64 + quad * 8;
  float4 v0 = *(const float4*)(fr);
  float4 v1 = *(const float4*)(fr + 4);
  float4 v2 = *(const float4*)(fr + 32);
  float4 v3 = *(const float4*)(fr + 36);
  uint4 o;
  int p;
  p = __builtin_amdgcn_cvt_pk_fp8_f32(v0.x, v0.y, 0, false);
  p = __builtin_amdgcn_cvt_pk_fp8_f32(v0.z, v0.w, p, true);  o.x = (unsigned)p;
  p = __builtin_amdgcn_cvt_pk_fp8_f32(v1.x, v1.y, 0, false);
  p = __builtin_amdgcn_cvt_pk_fp8_f32(v1.z, v1.w, p, true);  o.y = (unsigned)p;
  p = __builtin_amdgcn_cvt_pk_fp8_f32(v2.x, v2.y, 0, false);
  p = __builtin_amdgcn_cvt_pk_fp8_f32(v2.z, v2.w, p, true);  o.z = (unsigned)p;
  p = __builtin_amdgcn_cvt_pk_fp8_f32(v3.x, v3.y, 0, false);
  p = __builtin_amdgcn_cvt_pk_fp8_f32(v3.z, v3.w, p, true);  o.w = (unsigned)p;
  *(uint4*)(Fpk + (((size_t)g * 4 + k2) * 64 + lane) * 16) = o;
}

// ---- kernel 4: symmetric fused fp8 GEMM -> exp -> label-masked neg sums ----
// global_load_lds staging (fire-and-forget, 1 KB bursts), double-buffered over
// 4 K-slabs (one barrier each). Upper-triangle 1D tile grid, no dead blocks.
__global__ __launch_bounds__(256) void pass1_kernel(const unsigned char* __restrict__ Fpk,
                                                    const int* __restrict__ labp,
                                                    float* __restrict__ neg_sum) {
  __shared__ __align__(16) unsigned char sbuf[2][16384];  // [A 8K | B 8K] per buf
  __shared__ int rlab[128], clab[128];

  // decode linear upper-tri tile index
  int rT = 0, rem = blockIdx.x;
  while (rem >= NT1 - rT) { rem -= NT1 - rT; ++rT; }
  const int cT = rT + rem;

  const int tid = threadIdx.x;
  const int w = tid >> 6, lane = tid & 63;
  if (tid < 128) {
    rlab[tid] = labp[rT * 128 + tid];
    clab[tid] = labp[cT * 128 + tid];
  }
  const int wm = w >> 1, wn = w & 1;
  const int quad = lane >> 4, l16 = lane & 15;
  const int gA0 = rT * 8, gB0 = cT * 8;

#define STAGE1(k2, bsel)                                                            \
  {                                                                                 \
    _Pragma("unroll") for (int i_ = 0; i_ < 4; ++i_) {                              \
      int chunk = w * 4 + i_;                                                       \
      int g = (chunk < 8) ? gA0 + chunk : gB0 + chunk - 8;                          \
      async_copy16(Fpk + ((((size_t)g) * 4 + (k2)) * 64 + lane) * 16,               \
                   &sbuf[bsel][chunk * 1024 + lane * 16]);                          \
    }                                                                               \
  }

  f32x4 acc[4][4] = {};
  STAGE1(0, 0);
#pragma unroll
  for (int k2 = 0; k2 < 4; ++k2) {
    __syncthreads();                       // staged slab k2 ready
    if (k2 < 3) STAGE1(k2 + 1, (k2 + 1) & 1);
    long2_t af[4], bfr[4];
#pragma unroll
    for (int im = 0; im < 4; ++im)
      af[im] = *(const long2_t*)&sbuf[k2 & 1][(wm * 4 + im) * 1024 + lane * 16];
#pragma unroll
    for (int in = 0; in < 4; ++in)
      bfr[in] = *(const long2_t*)&sbuf[k2 & 1][8192 + (wn * 4 + in) * 1024 + lane * 16];
#pragma unroll
    for (int im = 0; im < 4; ++im)
#pragma unroll
      for (int in = 0; in < 4; ++in)
        acc[im][in] = __builtin_amdgcn_mfma_f32_16x16x32_fp8_fp8(af[im].x, bfr[in].x, acc[im][in], 0, 0, 0);
#pragma unroll
    for (int im = 0; im < 4; ++im)
#pragma unroll
      for (int in = 0; in < 4; ++in)
        acc[im][in] = __builtin_amdgcn_mfma_f32_16x16x32_fp8_fp8(af[im].y, bfr[in].y, acc[im][in], 0, 0, 0);
  }

  // C/D layout (m89): col = lane&15, row = quad*4 + reg
  const bool offDiag = (cT != rT);
  float cpart[4] = {0.f, 0.f, 0.f, 0.f};
#pragma unroll
  for (int im = 0; im < 4; ++im) {
    float rsum[4] = {0.f, 0.f, 0.f, 0.f};
#pragma unroll
    for (int in = 0; in < 4; ++in) {
      int lc = clab[wn * 64 + in * 16 + l16];
#pragma unroll
      for (int r = 0; r < 4; ++r) {
        int row = wm * 64 + im * 16 + quad * 4 + r;
        int rl = rlab[row];
        float e = __expf(acc[im][in][r] * INV_T);
        float me = (rl != lc && ((rl | lc) >= 0)) ? e : 0.0f;  // pads = -1
        rsum[r] += me;
        cpart[in] += me;
      }
    }
#pragma unroll
    for (int r = 0; r < 4; ++r) {
#pragma unroll
      for (int off = 1; off < 16; off <<= 1)
        rsum[r] += __shfl_xor(rsum[r], off, 64);
      if (l16 == 0)
        atomicAdd(&neg_sum[rT * 128 + wm * 64 + im * 16 + quad * 4 + r], rsum[r]);
    }
  }
  if (offDiag) {
#pragma unroll
    for (int in = 0; in < 4; ++in) {
      cpart[in] += __shfl_xor(cpart[in], 16, 64);
      cpart[in] += __shfl_xor(cpart[in], 32, 64);
      if (quad == 0)
        atomicAdd(&neg_sum[cT * 128 + wn * 64 + in * 16 + l16], cpart[in]);
    }
  }
}

// ---- kernel 5: block-diagonal positive-pair GEMM + fused loss epilogue ----
__global__ __launch_bounds__(256) void pass3_kernel(const unsigned char* __restrict__ Fpk,
                                                    const int* __restrict__ misc,
                                                    const float* __restrict__ neg_sum,
                                                    float* __restrict__ total_loss) {
  const int c = blockIdx.z;
  const int cnt = misc[M_CNT + c];
  if (cnt < 2 || cnt >= BN_) return;
  const int rT = blockIdx.y, cT = blockIdx.x;
  if (cT < rT) return;
  const int r0 = rT * 128, c0 = cT * 128;
  if (r0 >= cnt || c0 >= cnt) return;
  const int s16 = misc[M_START + c];
  const int sg = s16 >> 4;
  const int ng = ((cnt + 15) & ~15) >> 4;    // groups in this class's padded region

  __shared__ __align__(16) unsigned char sbuf[2][16384];
  __shared__ float rneg[128], cneg[128];
  const int tid = threadIdx.x;
  const int w = tid >> 6, lane = tid & 63;
  if (tid < 128) {
    rneg[tid] = neg_sum[s16 + min(r0 + tid, cnt - 1)];
    cneg[tid] = neg_sum[s16 + min(c0 + tid, cnt - 1)];
  }
  const int wm = w >> 1, wn = w & 1;
  const int quad = lane >> 4, l16 = lane & 15;

#define STAGE3(k2, bsel)                                                            \
  {                                                                                 \
    _Pragma("unroll") for (int i_ = 0; i_ < 4; ++i_) {                              \
      int chunk = w * 4 + i_;                                                       \
      int gl = (chunk < 8) ? rT * 8 + chunk : cT * 8 + chunk - 8;                   \
      int g = sg + min(gl, ng - 1);                                                 \
      async_copy16(Fpk + ((((size_t)g) * 4 + (k2)) * 64 + lane) * 16,               \
                   &sbuf[bsel][chunk * 1024 + lane * 16]);                          \
    }                                                                               \
  }

  f32x4 acc[4][4] = {};
  STAGE3(0, 0);
#pragma unroll
  for (int k2 = 0; k2 < 4; ++k2) {
    __syncthreads();
    if (k2 < 3) STAGE3(k2 + 1, (k2 + 1) & 1);
    long2_t af[4], bfr[4];
#pragma unroll
    for (int im = 0; im < 4; ++im)
      af[im] = *(const long2_t*)&sbuf[k2 & 1][(wm * 4 + im) * 1024 + lane * 16];
#pragma unroll
    for (int in = 0; in < 4; ++in)
      bfr[in] = *(const long2_t*)&sbuf[k2 & 1][8192 + (wn * 4 + in) * 1024 + lane * 16];
#pragma unroll
    for (int im = 0; im < 4; ++im)
#pragma unroll
      for (int in = 0; in < 4; ++in)
        acc[im][in] = __builtin_amdgcn_mfma_f32_16x16x32_fp8_fp8(af[im].x, bfr[in].x, acc[im][in], 0, 0, 0);
#pragma unroll
    for (int im = 0; im < 4; ++im)
#pragma unroll
      for (int in = 0; in < 4; ++in)
        acc[im][in] = __builtin_amdgcn_mfma_f32_16x16x32_fp8_fp8(af[im].y, bfr[in].y, acc[im][in], 0, 0, 0);
  }

  const bool offDiag = (cT != rT);
  float bsum = 0.f;
#pragma unroll
  for (int im = 0; im < 4; ++im) {
#pragma unroll
    for (int in = 0; in < 4; ++in) {
      int colIdx = wn * 64 + in * 16 + l16;
      int gc = c0 + colIdx;
      bool cok = gc < cnt;
#pragma unroll
      for (int r = 0; r < 4; ++r) {
        int rowIdx = wm * 64 + im * 16 + quad * 4 + r;
        int gr = r0 + rowIdx;
        if (cok && gr < cnt && gr != gc) {
          float e = __expf(acc[im][in][r] * INV_T);
          bsum -= __logf(e / (e + rneg[rowIdx]) + 1e-8f);
          if (offDiag)
            bsum -= __logf(e / (e + cneg[colIdx]) + 1e-8f);  // mirrored pair
        }
      }
    }
  }

  __shared__ float red[4];
#pragma unroll
  for (int off = 1; off < 64; off <<= 1) bsum += __shfl_xor(bsum, off, 64);
  if (lane == 0) red[w] = bsum;
  __syncthreads();
  if (tid == 0) {
    float s = red[0] + red[1] + red[2] + red[3];
    atomicAdd(total_loss, s / (float)(cnt - 1));   // /num_pos (uniform per class)
  }
}

// ---- kernel 6: finalize scalar ----
__global__ void finalize_kernel(const int* __restrict__ misc,
                                float* __restrict__ out) {
  float t = ((const float*)misc)[M_TOTAL];
  int n = misc[M_NV];
  out[0] = (n > 0) ? (t / (float)n) : 0.0f;
}

extern "C" void kernel_launch(void* const* d_in, const int* in_sizes, int n_in,
                              void* d_out, int out_size, void* d_ws, size_t ws_size,
                              hipStream_t stream) {
  (void)in_sizes; (void)n_in; (void)out_size; (void)ws_size;
  const float* F = (const float*)d_in[0];
  const int* labels = (const int*)d_in[1];
  float* out = (float*)d_out;
  char* ws = (char*)d_ws;

  // ws layout (~2.34 MB)
  unsigned char* Fpk = (unsigned char*)ws;                     // NGRP*4096 packed fp8
  float* neg_sum = (float*)(ws + (size_t)NGRP * 4096);         // NT1*128 floats
  int* misc = (int*)((char*)neg_sum + (size_t)NT1 * 128 * 4);  // 1024 ints
  int* permp = misc + 1024;                                    // BPAD ints
  int* labp = permp + BPAD;                                    // BPAD ints

  hist_kernel<<<32, 256, 0, stream>>>(labels, misc, permp, labp, neg_sum);
  scatter_kernel<<<32, 256, 0, stream>>>(labels, misc, permp, labp);
  convert_kernel<<<NGRP, 256, 0, stream>>>(F, permp, Fpk);
  pass1_kernel<<<NTILE1, 256, 0, stream>>>(Fpk, labp, neg_sum);
  // cnt up to 1024/class (8x8 tile grid); B=8192 random-16 gives ~512 +- 35
  pass3_kernel<<<dim3(8, 8, NCLS), 256, 0, stream>>>(Fpk, misc, neg_sum,
                                                     (float*)misc /* misc[0] */);
  finalize_kernel<<<1, 1, 0, stream>>>(misc, out);
}